// Round 6
// baseline (330.448 us; speedup 1.0000x reference)
//
#include <hip/hip_runtime.h>
#include <stdint.h>

#define NN 50000
#define NE 800000
#define NBINS 50001          // dst bins + 1 pad slot
#define H_OUT_OFF 6400000    // N*128, start of x_new in d_out

typedef float  f32x4  __attribute__((ext_vector_type(4)));
typedef short  bf16x8 __attribute__((ext_vector_type(8)));

static __device__ __forceinline__ unsigned short f2b(float f) {
  unsigned u = __float_as_uint(f);
  return (unsigned short)((u + 0x7fffu + ((u >> 16) & 1u)) >> 16);
}
static __device__ __forceinline__ float b2f(unsigned short h) {
  return __uint_as_float(((unsigned)h) << 16);
}

// ==== K1: hist (blocks 0..3124) | weight prep (3125..3508) | uc (3509) ====
__global__ void k1_kernel(const int* __restrict__ ei,
                          int* __restrict__ cnt,
                          unsigned short* __restrict__ rank,
                          const float* __restrict__ We1,
                          const float* __restrict__ We2,
                          const float* __restrict__ Wh1,
                          const float* __restrict__ Wh2,
                          const float* __restrict__ be2,
                          const float* __restrict__ Wx,
                          const float* __restrict__ bx,
                          unsigned short* __restrict__ We1Ttop,
                          unsigned short* __restrict__ We1Tbot,
                          unsigned short* __restrict__ We2T,
                          unsigned short* __restrict__ Wh1T,
                          unsigned short* __restrict__ Wh2T,
                          float* __restrict__ uvec) {
  int b = blockIdx.x, tid = threadIdx.x;
  if (b < 3125) {
    int i = b * 256 + tid;
    if (i < NE) rank[i] = (unsigned short)atomicAdd(&cnt[ei[NE + i]], 1);
    return;
  }
  b -= 3125;
  if (b < 384) {
    int i = b * 256 + tid;
    if (i < 16384) {                       // We1Ttop [128n][128k] (h_i dims)
      int n = i >> 7, k = i & 127;
      We1Ttop[i] = f2b(We1[k * 128 + n]);
    } else if (i < 32768) {                // We1Tbot (h_j dims, rows 128..255)
      int j = i - 16384; int n = j >> 7, k = j & 127;
      We1Tbot[j] = f2b(We1[(128 + k) * 128 + n]);
    } else if (i < 49152) {                // We2T [128][128]
      int j = i - 32768; int n = j >> 7, k = j & 127;
      We2T[j] = f2b(We2[k * 128 + n]);
    } else if (i < 81920) {                // Wh1T [128][256]
      int j = i - 49152; int n = j >> 8, k = j & 255;
      Wh1T[j] = f2b(Wh1[k * 128 + n]);
    } else if (i < 98304) {                // Wh2T [128][128]
      int j = i - 81920; int n = j >> 7, k = j & 127;
      Wh2T[j] = f2b(Wh2[k * 128 + n]);
    }
    return;
  }
  // uc: u = We2 @ Wx ; c = be2.Wx + bx
  int k = tid;
  if (k < 128) {
    float s = 0.f;
    for (int n = 0; n < 128; n++) s += We2[k * 128 + n] * Wx[n];
    uvec[k] = s;
  } else if (k == 128) {
    float s = 0.f;
    for (int n = 0; n < 128; n++) s += be2[n] * Wx[n];
    uvec[128] = s + bx[0];
  }
}

// ==== K2: single-block exclusive scan of 50001 bins ====
__global__ __launch_bounds__(1024)
void scan_kernel(const int* __restrict__ cnt, int* __restrict__ starts) {
  __shared__ int sS[1024];
  const int t = threadIdx.x;
  const int base = t * 49;
  int sum = 0;
  for (int i = 0; i < 49; i++) {
    int idx = base + i;
    if (idx < NBINS) sum += cnt[idx];
  }
  sS[t] = sum;
  __syncthreads();
  for (int off = 1; off < 1024; off <<= 1) {
    int v = (t >= off) ? sS[t - off] : 0;
    __syncthreads();
    sS[t] += v;
    __syncthreads();
  }
  int run = sS[t] - sum;       // exclusive prefix of this thread's chunk
  for (int i = 0; i < 49; i++) {
    int idx = base + i;
    if (idx < NBINS) { starts[idx] = run; run += cnt[idx]; }
  }
}

// ==== K3: scatter (blocks 0..3124) | yz GEMM (3125..3906) ====
__global__ __launch_bounds__(256, 4)
void k3_kernel(const int* __restrict__ ei,
               const unsigned short* __restrict__ rank,
               const int* __restrict__ starts,
               unsigned short* __restrict__ srcs,
               const float* __restrict__ node,
               const unsigned short* __restrict__ We1Ttop,
               const unsigned short* __restrict__ We1Tbot,
               const float* __restrict__ be1,
               unsigned short* __restrict__ Yb,
               unsigned short* __restrict__ Zb) {
  __shared__ __align__(16) unsigned short sA[64][136];
  const int tid = threadIdx.x;
  int b = blockIdx.x;

  if (b < 3125) {
    int i = b * 256 + tid;
    if (i < NE) {
      srcs[starts[ei[NE + i]] + (int)rank[i]] = (unsigned short)ei[i];
    }
    return;
  }
  b -= 3125;
  const int n0 = b * 64;

  for (int c = tid; c < 64 * 16; c += 256) {
    int e = c >> 4, s = c & 15;
    int n = n0 + e;
    if (n < NN) {
      const float* p = node + (size_t)n * 128 + s * 8;
      float4 v0 = *(const float4*)p;
      float4 v1 = *(const float4*)(p + 4);
      *(ushort4*)&sA[e][s * 8]     = make_ushort4(f2b(v0.x), f2b(v0.y), f2b(v0.z), f2b(v0.w));
      *(ushort4*)&sA[e][s * 8 + 4] = make_ushort4(f2b(v1.x), f2b(v1.y), f2b(v1.z), f2b(v1.w));
    } else {
      *(uint4*)&sA[e][s * 8] = make_uint4(0, 0, 0, 0);
    }
  }
  __syncthreads();

  const int wave = tid >> 6, lane = tid & 63;
  const int quad = lane >> 4, l16 = lane & 15;
  const int col0 = wave * 32 + l16, col1 = wave * 32 + 16 + l16;

  const f32x4 zero = {0.f, 0.f, 0.f, 0.f};
  f32x4 accY[4][2], accZ[4][2];
#pragma unroll
  for (int mt = 0; mt < 4; mt++) {
    accY[mt][0] = zero; accY[mt][1] = zero;
    accZ[mt][0] = zero; accZ[mt][1] = zero;
  }

#pragma unroll
  for (int kt = 0; kt < 4; kt++) {
    int kb = kt * 32 + quad * 8;
    bf16x8 by0 = *(const bf16x8*)(We1Ttop + (col0 << 7) + kb);
    bf16x8 by1 = *(const bf16x8*)(We1Ttop + (col1 << 7) + kb);
    bf16x8 bz0 = *(const bf16x8*)(We1Tbot + (col0 << 7) + kb);
    bf16x8 bz1 = *(const bf16x8*)(We1Tbot + (col1 << 7) + kb);
#pragma unroll
    for (int mt = 0; mt < 4; mt++) {
      bf16x8 a = *(const bf16x8*)&sA[mt * 16 + l16][kb];
      accY[mt][0] = __builtin_amdgcn_mfma_f32_16x16x32_bf16(a, by0, accY[mt][0], 0, 0, 0);
      accY[mt][1] = __builtin_amdgcn_mfma_f32_16x16x32_bf16(a, by1, accY[mt][1], 0, 0, 0);
      accZ[mt][0] = __builtin_amdgcn_mfma_f32_16x16x32_bf16(a, bz0, accZ[mt][0], 0, 0, 0);
      accZ[mt][1] = __builtin_amdgcn_mfma_f32_16x16x32_bf16(a, bz1, accZ[mt][1], 0, 0, 0);
    }
  }

  float sb0 = be1[col0], sb1 = be1[col1];
#pragma unroll
  for (int mt = 0; mt < 4; mt++) {
#pragma unroll
    for (int r = 0; r < 4; r++) {
      int row = mt * 16 + quad * 4 + r;
      int n = n0 + row;
      if (n < NN) {
        Yb[(size_t)n * 128 + col0] = f2b(accY[mt][0][r] + sb0);
        Yb[(size_t)n * 128 + col1] = f2b(accY[mt][1][r] + sb1);
        Zb[(size_t)n * 128 + col0] = f2b(accZ[mt][0][r]);
        Zb[(size_t)n * 128 + col1] = f2b(accZ[mt][1][r]);
      }
    }
  }
}

// ==== edge kernel: wave = one dst node; half-wave edge pairing ====
// lanes 0..31 process even edges, 32..63 odd edges; each lane owns 4 cols.
__global__ __launch_bounds__(256, 8)
void edge_kernel(const unsigned short* __restrict__ Zb,
                 const unsigned short* __restrict__ Yb,
                 const unsigned short* __restrict__ srcs,
                 const int* __restrict__ starts,
                 const float* __restrict__ coord,
                 const float* __restrict__ We1,   // row 256 = wsq
                 const float* __restrict__ uvec,  // u[0..127], c at [128]
                 float* __restrict__ T,
                 float* __restrict__ out) {
  __shared__ int    sSrc[4][64];
  __shared__ float4 sQ[4][64];

  const int tid = threadIdx.x, wave = tid >> 6, lane = tid & 63;
  const int n = blockIdx.x * 4 + wave;       // NN % 4 == 0, grid covers exactly
  const int half = lane >> 5, l32 = lane & 31;
  const int col = l32 * 4;

  const int start = starts[n], end = starts[n + 1];

  const float4 wsq = *(const float4*)(We1 + 256 * 128 + col);
  const float4 u   = *(const float4*)(uvec + col);
  const float  c   = uvec[128];
  ushort4 yv = *(const ushort4*)(Yb + (size_t)n * 128 + col);
  const float y0 = b2f(yv.x), y1 = b2f(yv.y), y2 = b2f(yv.z), y3 = b2f(yv.w);
  const float cdx = coord[n * 3 + 0], cdy = coord[n * 3 + 1], cdz = coord[n * 3 + 2];

  float aT0 = 0.f, aT1 = 0.f, aT2 = 0.f, aT3 = 0.f;
  float sx = 0.f, sy = 0.f, sz = 0.f;
  float dsx = 0.f, dsy = 0.f, dsz = 0.f;

  for (int cb = start; cb < end; cb += 64) {
    int m = end - cb; if (m > 64) m = 64;
    int s = 0; float dx = 0.f, dy = 0.f, dz = 0.f;
    if (lane < m) {
      s = (int)srcs[cb + lane];
      dx = cdx - coord[s * 3 + 0];
      dy = cdy - coord[s * 3 + 1];
      dz = cdz - coord[s * 3 + 2];
      dsx += dx; dsy += dy; dsz += dz;
    }
    sSrc[wave][lane] = s;
    sQ[wave][lane] = make_float4(dx, dy, dz, dx * dx + dy * dy + dz * dz);
    __builtin_amdgcn_wave_barrier();     // same-wave DS ops are in-order
    int pairs = (m + 1) >> 1;
    for (int p = 0; p < pairs; p++) {
      int idx = 2 * p + half;
      int ss = sSrc[wave][idx];
      float4 q = sQ[wave][idx];
      float valid = (idx < m) ? 1.f : 0.f;
      ushort4 zv = *(const ushort4*)(Zb + (size_t)ss * 128 + col);
      float t0 = fmaxf(b2f(zv.x) + y0 + q.w * wsq.x, 0.f) * valid;
      float t1 = fmaxf(b2f(zv.y) + y1 + q.w * wsq.y, 0.f) * valid;
      float t2 = fmaxf(b2f(zv.z) + y2 + q.w * wsq.z, 0.f) * valid;
      float t3 = fmaxf(b2f(zv.w) + y3 + q.w * wsq.w, 0.f) * valid;
      aT0 += t0; aT1 += t1; aT2 += t2; aT3 += t3;
      float tu = t0 * u.x + t1 * u.y + t2 * u.z + t3 * u.w;
      sx += tu * q.x; sy += tu * q.y; sz += tu * q.z;
    }
    __builtin_amdgcn_wave_barrier();
  }

  // combine even/odd half-wave accumulators, store T row (wave owns node n)
  aT0 += __shfl_xor(aT0, 32); aT1 += __shfl_xor(aT1, 32);
  aT2 += __shfl_xor(aT2, 32); aT3 += __shfl_xor(aT3, 32);
  if (half == 0) {
    *(float4*)&T[(size_t)n * 128 + col] = make_float4(aT0, aT1, aT2, aT3);
  }

  float px = sx + c * dsx, py = sy + c * dsy, pz = sz + c * dsz;
#pragma unroll
  for (int o = 1; o < 64; o <<= 1) {
    px += __shfl_xor(px, o); py += __shfl_xor(py, o); pz += __shfl_xor(pz, o);
  }
  if (lane == 0) {
    const float C = 1.0f / 49999.0f;
    out[H_OUT_OFF + n * 3 + 0] = cdx + C * px;
    out[H_OUT_OFF + n * 3 + 1] = cdy + C * py;
    out[H_OUT_OFF + n * 3 + 2] = cdz + C * pz;
  }
}

// ==== node kernel: m = T@We2 + deg*be2, then phi_h ====
__global__ __launch_bounds__(256, 3)
void node_kernel(const float* __restrict__ node,
                 const float* __restrict__ T,
                 const int* __restrict__ starts,
                 const unsigned short* __restrict__ We2T,
                 const float* __restrict__ be2,
                 const unsigned short* __restrict__ Wh1T,
                 const float* __restrict__ bh1,
                 const unsigned short* __restrict__ Wh2T,
                 const float* __restrict__ bh2,
                 float* __restrict__ out) {
  __shared__ __align__(16) unsigned short sA[64][264];
  __shared__ __align__(16) unsigned short sT[64][136];
  __shared__ float sDeg[64];

  const int tid = threadIdx.x;
  const int n0 = blockIdx.x * 64;

  if (tid < 64) {
    int n = n0 + tid;
    sDeg[tid] = (n < NN) ? (float)(starts[n + 1] - starts[n]) : 0.f;
  }

  for (int c = tid; c < 64 * 16; c += 256) {
    int e = c >> 4, s = c & 15;
    int n = n0 + e;
    if (n < NN) {
      const float* pn = node + (size_t)n * 128 + s * 8;
      float4 a0 = *(const float4*)pn;
      float4 a1 = *(const float4*)(pn + 4);
      *(ushort4*)&sA[e][s * 8]     = make_ushort4(f2b(a0.x), f2b(a0.y), f2b(a0.z), f2b(a0.w));
      *(ushort4*)&sA[e][s * 8 + 4] = make_ushort4(f2b(a1.x), f2b(a1.y), f2b(a1.z), f2b(a1.w));
      const float* p = T + (size_t)n * 128 + s * 8;
      float4 v0 = *(const float4*)p;
      float4 v1 = *(const float4*)(p + 4);
      *(ushort4*)&sT[e][s * 8]     = make_ushort4(f2b(v0.x), f2b(v0.y), f2b(v0.z), f2b(v0.w));
      *(ushort4*)&sT[e][s * 8 + 4] = make_ushort4(f2b(v1.x), f2b(v1.y), f2b(v1.z), f2b(v1.w));
    } else {
      *(uint4*)&sA[e][s * 8] = make_uint4(0, 0, 0, 0);
      *(uint4*)&sT[e][s * 8] = make_uint4(0, 0, 0, 0);
    }
  }
  __syncthreads();

  const int wave = tid >> 6, lane = tid & 63;
  const int quad = lane >> 4, l16 = lane & 15;
  const int col0 = wave * 32 + l16, col1 = wave * 32 + 16 + l16;

  const f32x4 zero = {0.f, 0.f, 0.f, 0.f};

  // GEMM1: m = T @ We2 (K=128)
  f32x4 accM[4][2];
#pragma unroll
  for (int mt = 0; mt < 4; mt++) { accM[mt][0] = zero; accM[mt][1] = zero; }
#pragma unroll
  for (int kt = 0; kt < 4; kt++) {
    int kb = kt * 32 + quad * 8;
    bf16x8 b0 = *(const bf16x8*)(We2T + (col0 << 7) + kb);
    bf16x8 b1 = *(const bf16x8*)(We2T + (col1 << 7) + kb);
#pragma unroll
    for (int mt = 0; mt < 4; mt++) {
      bf16x8 a = *(const bf16x8*)&sT[mt * 16 + l16][kb];
      accM[mt][0] = __builtin_amdgcn_mfma_f32_16x16x32_bf16(a, b0, accM[mt][0], 0, 0, 0);
      accM[mt][1] = __builtin_amdgcn_mfma_f32_16x16x32_bf16(a, b1, accM[mt][1], 0, 0, 0);
    }
  }
  {
    float eb0 = be2[col0], eb1 = be2[col1];
#pragma unroll
    for (int mt = 0; mt < 4; mt++) {
#pragma unroll
      for (int r = 0; r < 4; r++) {
        int row = mt * 16 + quad * 4 + r;
        float dg = sDeg[row];
        sA[row][128 + col0] = f2b(accM[mt][0][r] + dg * eb0);
        sA[row][128 + col1] = f2b(accM[mt][1][r] + dg * eb1);
      }
    }
  }
  __syncthreads();

  // GEMM2: [node|m] @ Wh1 (K=256), relu -> sT
  f32x4 acc[4][2];
#pragma unroll
  for (int mt = 0; mt < 4; mt++) { acc[mt][0] = zero; acc[mt][1] = zero; }
#pragma unroll
  for (int kt = 0; kt < 8; kt++) {
    int kb = kt * 32 + quad * 8;
    bf16x8 b0 = *(const bf16x8*)(Wh1T + (col0 << 8) + kb);
    bf16x8 b1 = *(const bf16x8*)(Wh1T + (col1 << 8) + kb);
#pragma unroll
    for (int mt = 0; mt < 4; mt++) {
      bf16x8 a = *(const bf16x8*)&sA[mt * 16 + l16][kb];
      acc[mt][0] = __builtin_amdgcn_mfma_f32_16x16x32_bf16(a, b0, acc[mt][0], 0, 0, 0);
      acc[mt][1] = __builtin_amdgcn_mfma_f32_16x16x32_bf16(a, b1, acc[mt][1], 0, 0, 0);
    }
  }
  {
    float sb0 = bh1[col0], sb1 = bh1[col1];
#pragma unroll
    for (int mt = 0; mt < 4; mt++) {
#pragma unroll
      for (int r = 0; r < 4; r++) {
        int row = mt * 16 + quad * 4 + r;
        sT[row][col0] = f2b(fmaxf(acc[mt][0][r] + sb0, 0.f));
        sT[row][col1] = f2b(fmaxf(acc[mt][1][r] + sb1, 0.f));
      }
    }
  }
  __syncthreads();

  // GEMM3: @ Wh2 (K=128) -> out
  f32x4 acc2[4][2];
#pragma unroll
  for (int mt = 0; mt < 4; mt++) { acc2[mt][0] = zero; acc2[mt][1] = zero; }
#pragma unroll
  for (int kt = 0; kt < 4; kt++) {
    int kb = kt * 32 + quad * 8;
    bf16x8 b0 = *(const bf16x8*)(Wh2T + (col0 << 7) + kb);
    bf16x8 b1 = *(const bf16x8*)(Wh2T + (col1 << 7) + kb);
#pragma unroll
    for (int mt = 0; mt < 4; mt++) {
      bf16x8 a = *(const bf16x8*)&sT[mt * 16 + l16][kb];
      acc2[mt][0] = __builtin_amdgcn_mfma_f32_16x16x32_bf16(a, b0, acc2[mt][0], 0, 0, 0);
      acc2[mt][1] = __builtin_amdgcn_mfma_f32_16x16x32_bf16(a, b1, acc2[mt][1], 0, 0, 0);
    }
  }
  {
    float eb0 = bh2[col0], eb1 = bh2[col1];
#pragma unroll
    for (int mt = 0; mt < 4; mt++) {
#pragma unroll
      for (int r = 0; r < 4; r++) {
        int row = mt * 16 + quad * 4 + r;
        int n = n0 + row;
        if (n < NN) {
          out[(size_t)n * 128 + col0] = acc2[mt][0][r] + eb0;
          out[(size_t)n * 128 + col1] = acc2[mt][1][r] + eb1;
        }
      }
    }
  }
}

extern "C" void kernel_launch(void* const* d_in, const int* in_sizes, int n_in,
                              void* d_out, int out_size, void* d_ws, size_t ws_size,
                              hipStream_t stream) {
  const float* node  = (const float*)d_in[0];
  const float* coord = (const float*)d_in[1];
  const int*   ei    = (const int*)d_in[2];
  const float* We1   = (const float*)d_in[3];
  const float* be1   = (const float*)d_in[4];
  const float* We2   = (const float*)d_in[5];
  const float* be2   = (const float*)d_in[6];
  const float* Wx    = (const float*)d_in[7];
  const float* bx    = (const float*)d_in[8];
  const float* Wh1   = (const float*)d_in[9];
  const float* bh1   = (const float*)d_in[10];
  const float* Wh2   = (const float*)d_in[11];
  const float* bh2   = (const float*)d_in[12];
  float* out = (float*)d_out;

  char* ws = (char*)d_ws;
  float*          T      = (float*)(ws);                       // 25,600,000
  int*            cnt    = (int*)  (ws + 25600000);            //    200,704
  int*            starts = (int*)  (ws + 25800704);            //    200,704
  unsigned short* rank   = (unsigned short*)(ws + 26001408);   //  1,600,000
  unsigned short* srcs   = (unsigned short*)(ws + 27601408);   //  1,600,000
  unsigned short* Yb     = (unsigned short*)(ws + 29201408);   // 12,800,000
  unsigned short* Zb     = (unsigned short*)(ws + 42001408);   // 12,800,000
  unsigned short* We1Ttop= (unsigned short*)(ws + 54801408);   //     32,768
  unsigned short* We1Tbot= (unsigned short*)(ws + 54834176);   //     32,768
  unsigned short* We2T   = (unsigned short*)(ws + 54866944);   //     32,768
  unsigned short* Wh1T   = (unsigned short*)(ws + 54899712);   //     65,536
  unsigned short* Wh2T   = (unsigned short*)(ws + 54965248);   //     32,768
  float*          uvec   = (float*)(ws + 54998016);            //        516

  hipMemsetAsync(cnt, 0, 200704, stream);

  k1_kernel<<<3510, 256, 0, stream>>>(ei, cnt, rank, We1, We2, Wh1, Wh2,
                                      be2, Wx, bx,
                                      We1Ttop, We1Tbot, We2T, Wh1T, Wh2T, uvec);
  scan_kernel<<<1, 1024, 0, stream>>>(cnt, starts);
  k3_kernel<<<3907, 256, 0, stream>>>(ei, rank, starts, srcs,
                                      node, We1Ttop, We1Tbot, be1, Yb, Zb);
  edge_kernel<<<NN / 4, 256, 0, stream>>>(Zb, Yb, srcs, starts, coord, We1, uvec,
                                          T, out);
  node_kernel<<<782, 256, 0, stream>>>(node, T, starts, We2T, be2,
                                       Wh1T, bh1, Wh2T, bh2, out);
}

// Round 7
// 242.035 us; speedup vs baseline: 1.3653x; 1.3653x over previous
//
#include <hip/hip_runtime.h>
#include <stdint.h>

#define NN 50000
#define NE 800000
#define NBINS 50001          // dst bins + 1 pad slot
#define H_OUT_OFF 6400000    // N*128, start of x_new in d_out

typedef float  f32x4  __attribute__((ext_vector_type(4)));
typedef short  bf16x8 __attribute__((ext_vector_type(8)));

static __device__ __forceinline__ unsigned short f2b(float f) {
  unsigned u = __float_as_uint(f);
  return (unsigned short)((u + 0x7fffu + ((u >> 16) & 1u)) >> 16);
}
static __device__ __forceinline__ float b2f(unsigned short h) {
  return __uint_as_float(((unsigned)h) << 16);
}

// ==== K1: hist (blocks 0..3124) | weight prep (3125..3508) | uc (3509) ====
__global__ void k1_kernel(const int* __restrict__ ei,
                          int* __restrict__ cnt,
                          unsigned short* __restrict__ rank,
                          const float* __restrict__ We1,
                          const float* __restrict__ We2,
                          const float* __restrict__ Wh1,
                          const float* __restrict__ Wh2,
                          const float* __restrict__ be2,
                          const float* __restrict__ Wx,
                          const float* __restrict__ bx,
                          unsigned short* __restrict__ We1Ttop,
                          unsigned short* __restrict__ We1Tbot,
                          unsigned short* __restrict__ We2T,
                          unsigned short* __restrict__ Wh1T,
                          unsigned short* __restrict__ Wh2T,
                          float* __restrict__ uvec) {
  int b = blockIdx.x, tid = threadIdx.x;
  if (b < 3125) {
    int i = b * 256 + tid;
    if (i < NE) rank[i] = (unsigned short)atomicAdd(&cnt[ei[NE + i]], 1);
    return;
  }
  b -= 3125;
  if (b < 384) {
    int i = b * 256 + tid;
    if (i < 16384) {                       // We1Ttop [128n][128k] (h_i dims)
      int n = i >> 7, k = i & 127;
      We1Ttop[i] = f2b(We1[k * 128 + n]);
    } else if (i < 32768) {                // We1Tbot (h_j dims, rows 128..255)
      int j = i - 16384; int n = j >> 7, k = j & 127;
      We1Tbot[j] = f2b(We1[(128 + k) * 128 + n]);
    } else if (i < 49152) {                // We2T [128][128]
      int j = i - 32768; int n = j >> 7, k = j & 127;
      We2T[j] = f2b(We2[k * 128 + n]);
    } else if (i < 81920) {                // Wh1T [128][256]
      int j = i - 49152; int n = j >> 8, k = j & 255;
      Wh1T[j] = f2b(Wh1[k * 128 + n]);
    } else if (i < 98304) {                // Wh2T [128][128]
      int j = i - 81920; int n = j >> 7, k = j & 127;
      Wh2T[j] = f2b(Wh2[k * 128 + n]);
    }
    return;
  }
  // uc: u = We2 @ Wx ; c = be2.Wx + bx
  int k = tid;
  if (k < 128) {
    float s = 0.f;
    for (int n = 0; n < 128; n++) s += We2[k * 128 + n] * Wx[n];
    uvec[k] = s;
  } else if (k == 128) {
    float s = 0.f;
    for (int n = 0; n < 128; n++) s += be2[n] * Wx[n];
    uvec[128] = s + bx[0];
  }
}

// ==== scanA: per-block reduction of 256 bins -> bsum[196] ====
__global__ void scanA_kernel(const int* __restrict__ cnt, int* __restrict__ bsum) {
  __shared__ int sd[256];
  int b = blockIdx.x, t = threadIdx.x, i = b * 256 + t;
  sd[t] = (i < NBINS) ? cnt[i] : 0;
  __syncthreads();
  for (int s = 128; s; s >>= 1) {
    if (t < s) sd[t] += sd[t + s];
    __syncthreads();
  }
  if (t == 0) bsum[b] = sd[0];
}

// ==== scanC: each block derives its offset from bsum (redundant tiny scan),
//      then scans its own 256 bins -> starts ====
__global__ void scanC_kernel(const int* __restrict__ cnt, const int* __restrict__ bsum,
                             int* __restrict__ starts) {
  __shared__ int sd[256];
  int b = blockIdx.x, t = threadIdx.x, i = b * 256 + t;
  // inclusive scan of bsum (196 valid entries)
  int bv = (t < 196) ? bsum[t] : 0;
  sd[t] = bv;
  __syncthreads();
  for (int off = 1; off < 256; off <<= 1) {
    int x = (t >= off) ? sd[t - off] : 0;
    __syncthreads();
    sd[t] += x;
    __syncthreads();
  }
  int boff = (b > 0) ? sd[b - 1] : 0;    // exclusive prefix of block b (broadcast)
  __syncthreads();
  // scan this block's 256 bins
  int v = (i < NBINS) ? cnt[i] : 0;
  sd[t] = v;
  __syncthreads();
  for (int off = 1; off < 256; off <<= 1) {
    int x = (t >= off) ? sd[t - off] : 0;
    __syncthreads();
    sd[t] += x;
    __syncthreads();
  }
  if (i < NBINS) starts[i] = sd[t] - v + boff;
}

// ==== K3: scatter (blocks 0..3124) | yz GEMM (3125..3906) ====
__global__ __launch_bounds__(256, 4)
void k3_kernel(const int* __restrict__ ei,
               const unsigned short* __restrict__ rank,
               const int* __restrict__ starts,
               unsigned short* __restrict__ srcs,
               const float* __restrict__ node,
               const unsigned short* __restrict__ We1Ttop,
               const unsigned short* __restrict__ We1Tbot,
               const float* __restrict__ be1,
               unsigned short* __restrict__ Yb,
               unsigned short* __restrict__ Zb) {
  __shared__ __align__(16) unsigned short sA[64][136];
  const int tid = threadIdx.x;
  int b = blockIdx.x;

  if (b < 3125) {
    int i = b * 256 + tid;
    if (i < NE) {
      srcs[starts[ei[NE + i]] + (int)rank[i]] = (unsigned short)ei[i];
    }
    return;
  }
  b -= 3125;
  const int n0 = b * 64;

  for (int c = tid; c < 64 * 16; c += 256) {
    int e = c >> 4, s = c & 15;
    int n = n0 + e;
    if (n < NN) {
      const float* p = node + (size_t)n * 128 + s * 8;
      float4 v0 = *(const float4*)p;
      float4 v1 = *(const float4*)(p + 4);
      *(ushort4*)&sA[e][s * 8]     = make_ushort4(f2b(v0.x), f2b(v0.y), f2b(v0.z), f2b(v0.w));
      *(ushort4*)&sA[e][s * 8 + 4] = make_ushort4(f2b(v1.x), f2b(v1.y), f2b(v1.z), f2b(v1.w));
    } else {
      *(uint4*)&sA[e][s * 8] = make_uint4(0, 0, 0, 0);
    }
  }
  __syncthreads();

  const int wave = tid >> 6, lane = tid & 63;
  const int quad = lane >> 4, l16 = lane & 15;
  const int col0 = wave * 32 + l16, col1 = wave * 32 + 16 + l16;

  const f32x4 zero = {0.f, 0.f, 0.f, 0.f};
  f32x4 accY[4][2], accZ[4][2];
#pragma unroll
  for (int mt = 0; mt < 4; mt++) {
    accY[mt][0] = zero; accY[mt][1] = zero;
    accZ[mt][0] = zero; accZ[mt][1] = zero;
  }

#pragma unroll
  for (int kt = 0; kt < 4; kt++) {
    int kb = kt * 32 + quad * 8;
    bf16x8 by0 = *(const bf16x8*)(We1Ttop + (col0 << 7) + kb);
    bf16x8 by1 = *(const bf16x8*)(We1Ttop + (col1 << 7) + kb);
    bf16x8 bz0 = *(const bf16x8*)(We1Tbot + (col0 << 7) + kb);
    bf16x8 bz1 = *(const bf16x8*)(We1Tbot + (col1 << 7) + kb);
#pragma unroll
    for (int mt = 0; mt < 4; mt++) {
      bf16x8 a = *(const bf16x8*)&sA[mt * 16 + l16][kb];
      accY[mt][0] = __builtin_amdgcn_mfma_f32_16x16x32_bf16(a, by0, accY[mt][0], 0, 0, 0);
      accY[mt][1] = __builtin_amdgcn_mfma_f32_16x16x32_bf16(a, by1, accY[mt][1], 0, 0, 0);
      accZ[mt][0] = __builtin_amdgcn_mfma_f32_16x16x32_bf16(a, bz0, accZ[mt][0], 0, 0, 0);
      accZ[mt][1] = __builtin_amdgcn_mfma_f32_16x16x32_bf16(a, bz1, accZ[mt][1], 0, 0, 0);
    }
  }

  float sb0 = be1[col0], sb1 = be1[col1];
#pragma unroll
  for (int mt = 0; mt < 4; mt++) {
#pragma unroll
    for (int r = 0; r < 4; r++) {
      int row = mt * 16 + quad * 4 + r;
      int n = n0 + row;
      if (n < NN) {
        Yb[(size_t)n * 128 + col0] = f2b(accY[mt][0][r] + sb0);
        Yb[(size_t)n * 128 + col1] = f2b(accY[mt][1][r] + sb1);
        Zb[(size_t)n * 128 + col0] = f2b(accZ[mt][0][r]);
        Zb[(size_t)n * 128 + col1] = f2b(accZ[mt][1][r]);
      }
    }
  }
}

// ==== edge kernel: wave = one dst node; half-wave edge pairing ====
__global__ __launch_bounds__(256, 8)
void edge_kernel(const unsigned short* __restrict__ Zb,
                 const unsigned short* __restrict__ Yb,
                 const unsigned short* __restrict__ srcs,
                 const int* __restrict__ starts,
                 const float* __restrict__ coord,
                 const float* __restrict__ We1,   // row 256 = wsq
                 const float* __restrict__ uvec,  // u[0..127], c at [128]
                 float* __restrict__ T,
                 float* __restrict__ out) {
  __shared__ int    sSrc[4][64];
  __shared__ float4 sQ[4][64];

  const int tid = threadIdx.x, wave = tid >> 6, lane = tid & 63;
  const int n = blockIdx.x * 4 + wave;       // NN % 4 == 0, grid covers exactly
  const int half = lane >> 5, l32 = lane & 31;
  const int col = l32 * 4;

  const int start = starts[n], end = starts[n + 1];

  const float4 wsq = *(const float4*)(We1 + 256 * 128 + col);
  const float4 u   = *(const float4*)(uvec + col);
  const float  c   = uvec[128];
  ushort4 yv = *(const ushort4*)(Yb + (size_t)n * 128 + col);
  const float y0 = b2f(yv.x), y1 = b2f(yv.y), y2 = b2f(yv.z), y3 = b2f(yv.w);
  const float cdx = coord[n * 3 + 0], cdy = coord[n * 3 + 1], cdz = coord[n * 3 + 2];

  float aT0 = 0.f, aT1 = 0.f, aT2 = 0.f, aT3 = 0.f;
  float sx = 0.f, sy = 0.f, sz = 0.f;
  float dsx = 0.f, dsy = 0.f, dsz = 0.f;

  for (int cb = start; cb < end; cb += 64) {
    int m = end - cb; if (m > 64) m = 64;
    int s = 0; float dx = 0.f, dy = 0.f, dz = 0.f;
    if (lane < m) {
      s = (int)srcs[cb + lane];
      dx = cdx - coord[s * 3 + 0];
      dy = cdy - coord[s * 3 + 1];
      dz = cdz - coord[s * 3 + 2];
      dsx += dx; dsy += dy; dsz += dz;
    }
    sSrc[wave][lane] = s;
    sQ[wave][lane] = make_float4(dx, dy, dz, dx * dx + dy * dy + dz * dz);
    __builtin_amdgcn_wave_barrier();     // same-wave DS ops are in-order
    int pairs = (m + 1) >> 1;
    for (int p = 0; p < pairs; p++) {
      int idx = 2 * p + half;
      int ss = sSrc[wave][idx];
      float4 q = sQ[wave][idx];
      float valid = (idx < m) ? 1.f : 0.f;
      ushort4 zv = *(const ushort4*)(Zb + (size_t)ss * 128 + col);
      float t0 = fmaxf(b2f(zv.x) + y0 + q.w * wsq.x, 0.f) * valid;
      float t1 = fmaxf(b2f(zv.y) + y1 + q.w * wsq.y, 0.f) * valid;
      float t2 = fmaxf(b2f(zv.z) + y2 + q.w * wsq.z, 0.f) * valid;
      float t3 = fmaxf(b2f(zv.w) + y3 + q.w * wsq.w, 0.f) * valid;
      aT0 += t0; aT1 += t1; aT2 += t2; aT3 += t3;
      float tu = t0 * u.x + t1 * u.y + t2 * u.z + t3 * u.w;
      sx += tu * q.x; sy += tu * q.y; sz += tu * q.z;
    }
    __builtin_amdgcn_wave_barrier();
  }

  aT0 += __shfl_xor(aT0, 32); aT1 += __shfl_xor(aT1, 32);
  aT2 += __shfl_xor(aT2, 32); aT3 += __shfl_xor(aT3, 32);
  if (half == 0) {
    *(float4*)&T[(size_t)n * 128 + col] = make_float4(aT0, aT1, aT2, aT3);
  }

  float px = sx + c * dsx, py = sy + c * dsy, pz = sz + c * dsz;
#pragma unroll
  for (int o = 1; o < 64; o <<= 1) {
    px += __shfl_xor(px, o); py += __shfl_xor(py, o); pz += __shfl_xor(pz, o);
  }
  if (lane == 0) {
    const float C = 1.0f / 49999.0f;
    out[H_OUT_OFF + n * 3 + 0] = cdx + C * px;
    out[H_OUT_OFF + n * 3 + 1] = cdy + C * py;
    out[H_OUT_OFF + n * 3 + 2] = cdz + C * pz;
  }
}

// ==== node kernel: m = T@We2 + deg*be2, then phi_h ====
__global__ __launch_bounds__(256, 3)
void node_kernel(const float* __restrict__ node,
                 const float* __restrict__ T,
                 const int* __restrict__ starts,
                 const unsigned short* __restrict__ We2T,
                 const float* __restrict__ be2,
                 const unsigned short* __restrict__ Wh1T,
                 const float* __restrict__ bh1,
                 const unsigned short* __restrict__ Wh2T,
                 const float* __restrict__ bh2,
                 float* __restrict__ out) {
  __shared__ __align__(16) unsigned short sA[64][264];
  __shared__ __align__(16) unsigned short sT[64][136];
  __shared__ float sDeg[64];

  const int tid = threadIdx.x;
  const int n0 = blockIdx.x * 64;

  if (tid < 64) {
    int n = n0 + tid;
    sDeg[tid] = (n < NN) ? (float)(starts[n + 1] - starts[n]) : 0.f;
  }

  for (int c = tid; c < 64 * 16; c += 256) {
    int e = c >> 4, s = c & 15;
    int n = n0 + e;
    if (n < NN) {
      const float* pn = node + (size_t)n * 128 + s * 8;
      float4 a0 = *(const float4*)pn;
      float4 a1 = *(const float4*)(pn + 4);
      *(ushort4*)&sA[e][s * 8]     = make_ushort4(f2b(a0.x), f2b(a0.y), f2b(a0.z), f2b(a0.w));
      *(ushort4*)&sA[e][s * 8 + 4] = make_ushort4(f2b(a1.x), f2b(a1.y), f2b(a1.z), f2b(a1.w));
      const float* p = T + (size_t)n * 128 + s * 8;
      float4 v0 = *(const float4*)p;
      float4 v1 = *(const float4*)(p + 4);
      *(ushort4*)&sT[e][s * 8]     = make_ushort4(f2b(v0.x), f2b(v0.y), f2b(v0.z), f2b(v0.w));
      *(ushort4*)&sT[e][s * 8 + 4] = make_ushort4(f2b(v1.x), f2b(v1.y), f2b(v1.z), f2b(v1.w));
    } else {
      *(uint4*)&sA[e][s * 8] = make_uint4(0, 0, 0, 0);
      *(uint4*)&sT[e][s * 8] = make_uint4(0, 0, 0, 0);
    }
  }
  __syncthreads();

  const int wave = tid >> 6, lane = tid & 63;
  const int quad = lane >> 4, l16 = lane & 15;
  const int col0 = wave * 32 + l16, col1 = wave * 32 + 16 + l16;

  const f32x4 zero = {0.f, 0.f, 0.f, 0.f};

  // GEMM1: m = T @ We2 (K=128)
  f32x4 accM[4][2];
#pragma unroll
  for (int mt = 0; mt < 4; mt++) { accM[mt][0] = zero; accM[mt][1] = zero; }
#pragma unroll
  for (int kt = 0; kt < 4; kt++) {
    int kb = kt * 32 + quad * 8;
    bf16x8 b0 = *(const bf16x8*)(We2T + (col0 << 7) + kb);
    bf16x8 b1 = *(const bf16x8*)(We2T + (col1 << 7) + kb);
#pragma unroll
    for (int mt = 0; mt < 4; mt++) {
      bf16x8 a = *(const bf16x8*)&sT[mt * 16 + l16][kb];
      accM[mt][0] = __builtin_amdgcn_mfma_f32_16x16x32_bf16(a, b0, accM[mt][0], 0, 0, 0);
      accM[mt][1] = __builtin_amdgcn_mfma_f32_16x16x32_bf16(a, b1, accM[mt][1], 0, 0, 0);
    }
  }
  {
    float eb0 = be2[col0], eb1 = be2[col1];
#pragma unroll
    for (int mt = 0; mt < 4; mt++) {
#pragma unroll
      for (int r = 0; r < 4; r++) {
        int row = mt * 16 + quad * 4 + r;
        float dg = sDeg[row];
        sA[row][128 + col0] = f2b(accM[mt][0][r] + dg * eb0);
        sA[row][128 + col1] = f2b(accM[mt][1][r] + dg * eb1);
      }
    }
  }
  __syncthreads();

  // GEMM2: [node|m] @ Wh1 (K=256), relu -> sT
  f32x4 acc[4][2];
#pragma unroll
  for (int mt = 0; mt < 4; mt++) { acc[mt][0] = zero; acc[mt][1] = zero; }
#pragma unroll
  for (int kt = 0; kt < 8; kt++) {
    int kb = kt * 32 + quad * 8;
    bf16x8 b0 = *(const bf16x8*)(Wh1T + (col0 << 8) + kb);
    bf16x8 b1 = *(const bf16x8*)(Wh1T + (col1 << 8) + kb);
#pragma unroll
    for (int mt = 0; mt < 4; mt++) {
      bf16x8 a = *(const bf16x8*)&sA[mt * 16 + l16][kb];
      acc[mt][0] = __builtin_amdgcn_mfma_f32_16x16x32_bf16(a, b0, acc[mt][0], 0, 0, 0);
      acc[mt][1] = __builtin_amdgcn_mfma_f32_16x16x32_bf16(a, b1, acc[mt][1], 0, 0, 0);
    }
  }
  {
    float sb0 = bh1[col0], sb1 = bh1[col1];
#pragma unroll
    for (int mt = 0; mt < 4; mt++) {
#pragma unroll
      for (int r = 0; r < 4; r++) {
        int row = mt * 16 + quad * 4 + r;
        sT[row][col0] = f2b(fmaxf(acc[mt][0][r] + sb0, 0.f));
        sT[row][col1] = f2b(fmaxf(acc[mt][1][r] + sb1, 0.f));
      }
    }
  }
  __syncthreads();

  // GEMM3: @ Wh2 (K=128) -> out
  f32x4 acc2[4][2];
#pragma unroll
  for (int mt = 0; mt < 4; mt++) { acc2[mt][0] = zero; acc2[mt][1] = zero; }
#pragma unroll
  for (int kt = 0; kt < 4; kt++) {
    int kb = kt * 32 + quad * 8;
    bf16x8 b0 = *(const bf16x8*)(Wh2T + (col0 << 7) + kb);
    bf16x8 b1 = *(const bf16x8*)(Wh2T + (col1 << 7) + kb);
#pragma unroll
    for (int mt = 0; mt < 4; mt++) {
      bf16x8 a = *(const bf16x8*)&sT[mt * 16 + l16][kb];
      acc2[mt][0] = __builtin_amdgcn_mfma_f32_16x16x32_bf16(a, b0, acc2[mt][0], 0, 0, 0);
      acc2[mt][1] = __builtin_amdgcn_mfma_f32_16x16x32_bf16(a, b1, acc2[mt][1], 0, 0, 0);
    }
  }
  {
    float eb0 = bh2[col0], eb1 = bh2[col1];
#pragma unroll
    for (int mt = 0; mt < 4; mt++) {
#pragma unroll
      for (int r = 0; r < 4; r++) {
        int row = mt * 16 + quad * 4 + r;
        int n = n0 + row;
        if (n < NN) {
          out[(size_t)n * 128 + col0] = acc2[mt][0][r] + eb0;
          out[(size_t)n * 128 + col1] = acc2[mt][1][r] + eb1;
        }
      }
    }
  }
}

extern "C" void kernel_launch(void* const* d_in, const int* in_sizes, int n_in,
                              void* d_out, int out_size, void* d_ws, size_t ws_size,
                              hipStream_t stream) {
  const float* node  = (const float*)d_in[0];
  const float* coord = (const float*)d_in[1];
  const int*   ei    = (const int*)d_in[2];
  const float* We1   = (const float*)d_in[3];
  const float* be1   = (const float*)d_in[4];
  const float* We2   = (const float*)d_in[5];
  const float* be2   = (const float*)d_in[6];
  const float* Wx    = (const float*)d_in[7];
  const float* bx    = (const float*)d_in[8];
  const float* Wh1   = (const float*)d_in[9];
  const float* bh1   = (const float*)d_in[10];
  const float* Wh2   = (const float*)d_in[11];
  const float* bh2   = (const float*)d_in[12];
  float* out = (float*)d_out;

  char* ws = (char*)d_ws;
  float*          T      = (float*)(ws);                       // 25,600,000
  int*            cnt    = (int*)  (ws + 25600000);            //    200,704
  int*            starts = (int*)  (ws + 25800704);            //    200,704
  int*            bsum   = (int*)  (ws + 26001408);            //      1,024
  unsigned short* rank   = (unsigned short*)(ws + 26002432);   //  1,600,000
  unsigned short* srcs   = (unsigned short*)(ws + 27602432);   //  1,600,000
  unsigned short* Yb     = (unsigned short*)(ws + 29202432);   // 12,800,000
  unsigned short* Zb     = (unsigned short*)(ws + 42002432);   // 12,800,000
  unsigned short* We1Ttop= (unsigned short*)(ws + 54802432);   //     32,768
  unsigned short* We1Tbot= (unsigned short*)(ws + 54835200);   //     32,768
  unsigned short* We2T   = (unsigned short*)(ws + 54867968);   //     32,768
  unsigned short* Wh1T   = (unsigned short*)(ws + 54900736);   //     65,536
  unsigned short* Wh2T   = (unsigned short*)(ws + 54966272);   //     32,768
  float*          uvec   = (float*)(ws + 54999040);            //        516

  hipMemsetAsync(cnt, 0, 200704, stream);

  k1_kernel<<<3510, 256, 0, stream>>>(ei, cnt, rank, We1, We2, Wh1, Wh2,
                                      be2, Wx, bx,
                                      We1Ttop, We1Tbot, We2T, Wh1T, Wh2T, uvec);
  scanA_kernel<<<196, 256, 0, stream>>>(cnt, bsum);
  scanC_kernel<<<196, 256, 0, stream>>>(cnt, bsum, starts);
  k3_kernel<<<3907, 256, 0, stream>>>(ei, rank, starts, srcs,
                                      node, We1Ttop, We1Tbot, be1, Yb, Zb);
  edge_kernel<<<NN / 4, 256, 0, stream>>>(Zb, Yb, srcs, starts, coord, We1, uvec,
                                          T, out);
  node_kernel<<<782, 256, 0, stream>>>(node, T, starts, We2T, be2,
                                       Wh1T, bh1, Wh2T, bh2, out);
}